// Round 12
// baseline (356.525 us; speedup 1.0000x reference)
//
#include <hip/hip_runtime.h>
#include <stdint.h>

// TopoSignature via parallel Boruvka MST. Round 12: scan+hook fused into one
// dispatch per round (25 -> 13 dispatches). Key differences vs the failed r8
// fusion: (a) all cross-block scan writes are ATOMICS (coherent without any
// fence; round-1 best write = atomicExch, also removing poison dependency);
// (b) blocks drain only their OWN vmem (s_waitcnt vmcnt(0)) before a
// TWO-LEVEL ticket (64x16 -> 1x64, bounds same-address serialization) — no
// per-block __threadfence/wbL2; (c) the hook-elect block works in LDS
// (16 KB nxt[] only -> occupancy stays 8/CU) and reads best via
// __hip_atomic_load (agent scope, bypasses stale L1/L2 lines cached by scan
// read-checks). comp/edges/best-reset are plain stores: hook-elect is the
// only dirty writer this dispatch; kernel-end flush publishes for the next.
// Sentinel/edge writes live ONLY in the hook phase (no two-dirty-L2 races).

#define N        4096
#define NROUNDS  12

typedef unsigned long long u64;
typedef uint32_t u32;

#define INFK (~0ull)

struct Ws {
    u64 best[2][N];          // per-component min outgoing edge key
    u32 comp[2][N];          // vertex -> component root label
    u32 edges[2][N];         // edge per dying root, (lo<<12)|hi; (i<<12)|i sentinel
    u32 ncomp[2];
    u32 tick1[NROUNDS][2][64];   // ticket leaves (16 blocks each) — memset 0
    u32 tick2[NROUNDS][2];       // ticket roots (64 arrivals)     — memset 0
    u64 bm[2][N * 64];       // per-row per-lane-block bound keys: (wbits<<12)|col
};

__device__ __forceinline__ u64 umin64(u64 a, u64 b) { return a < b ? a : b; }

__device__ __forceinline__ u64 shfl_xor_u64(u64 x, int off) {
    u32 lo = (u32)x, hi = (u32)(x >> 32);
    lo = (u32)__shfl_xor((int)lo, off, 64);
    hi = (u32)__shfl_xor((int)hi, off, 64);
    return ((u64)hi << 32) | lo;
}

// blocks 0..1023: matrix 0 (rows 4b..4b+3, one wave each); 1024..2047: matrix 1.
__launch_bounds__(256, 8)
__global__ void round_k(const float* __restrict__ d1, const float* __restrict__ d2,
                        Ws* __restrict__ ws, float* __restrict__ out,
                        int r, int fin) {
    const int m = blockIdx.x >> 10;
    const int b = blockIdx.x & 1023;
    const int tid = threadIdx.x, wave = tid >> 6, lane = tid & 63;
    const int v = (b << 2) + wave;
    u32* __restrict__ cm   = ws->comp[m];
    u64* __restrict__ best = ws->best[m];
    const float* __restrict__ dm = m ? d2 : d1;

    bool alive = true;
    if (r > 1) alive = (ws->ncomp[m] > 1u);       // uniform per block

    // ---------------- scan phase ----------------
    if (alive) {
        if (r == 1) {
            // full scan; lane-private block min (block L = cols ≡ [4L,4L+4) mod 256)
            const float4* __restrict__ row4 = (const float4*)(dm + (size_t)v * N);
            const u32 uv = (u32)v;
            u64 bmin = INFK;
            #pragma unroll
            for (int j = 0; j < 16; ++j) {
                const int c = lane + 64 * j;
                float4 w = row4[c];
                const u32 c0 = (u32)(4 * c);
                if (c0 + 0 != uv) bmin = umin64(bmin, (((u64)__float_as_uint(w.x)) << 12) | (c0 + 0));
                if (c0 + 1 != uv) bmin = umin64(bmin, (((u64)__float_as_uint(w.y)) << 12) | (c0 + 1));
                if (c0 + 2 != uv) bmin = umin64(bmin, (((u64)__float_as_uint(w.z)) << 12) | (c0 + 2));
                if (c0 + 3 != uv) bmin = umin64(bmin, (((u64)__float_as_uint(w.w)) << 12) | (c0 + 3));
            }
            ws->bm[m][(size_t)v * 64 + lane] = bmin;      // plain: read next dispatch
            u64 rowmin = bmin;
            #pragma unroll
            for (int off = 1; off <= 32; off <<= 1)
                rowmin = umin64(rowmin, shfl_xor_u64(rowmin, off));
            if (lane == 0) {
                u32 u  = (u32)rowmin & 0xFFFu;
                u64 wb = rowmin >> 12;
                u32 lo = min((u32)v, u), hi = max((u32)v, u);
                // atomicExch: coherent-point write, unique writer, no init needed
                atomicExch(&best[v], (wb << 24) | ((u64)lo << 12) | (u64)hi);
            }
        } else {
            // bound-table pruned scan. lane = block.
            u64* __restrict__ bmrow = ws->bm[m] + (size_t)v * 64;
            const u32 cv = cm[v];
            u64 key = bmrow[lane];
            bool cross = false;
            if (key != INFK) cross = (cm[(u32)key & 0xFFFu] != cv);

            u64 kb = cross ? key : INFK;           // exact cross candidates
            #pragma unroll
            for (int off = 1; off <= 32; off <<= 1)
                kb = umin64(kb, shfl_xor_u64(kb, off));

            const bool need = (!cross) && (key < kb);
            u64 nm = INFK;
            if (need) {
                const float4* __restrict__ row4 = (const float4*)(dm + (size_t)v * N);
                const uint4*  __restrict__ c4   = (const uint4*)cm;
                #pragma unroll
                for (int j = 0; j < 16; ++j) {
                    const int c = lane + 64 * j;
                    float4 w = row4[c];
                    uint4 cu = c4[c];
                    u32 c0 = (u32)(4 * c);
                    if (cu.x != cv) nm = umin64(nm, (((u64)__float_as_uint(w.x)) << 12) | (c0 + 0));
                    if (cu.y != cv) nm = umin64(nm, (((u64)__float_as_uint(w.y)) << 12) | (c0 + 1));
                    if (cu.z != cv) nm = umin64(nm, (((u64)__float_as_uint(w.z)) << 12) | (c0 + 2));
                    if (cu.w != cv) nm = umin64(nm, (((u64)__float_as_uint(w.w)) << 12) | (c0 + 3));
                }
                bmrow[lane] = nm;                  // tightened bound (plain)
            }
            u64 kb2 = need ? nm : INFK;
            #pragma unroll
            for (int off = 1; off <= 32; off <<= 1)
                kb2 = umin64(kb2, shfl_xor_u64(kb2, off));

            u64 fin2 = umin64(kb, kb2);
            if (lane == 0 && fin2 != INFK) {
                u32 u  = (u32)fin2 & 0xFFFu;
                u64 wb = fin2 >> 12;
                u32 lo = min((u32)v, u), hi = max((u32)v, u);
                u64 g  = (wb << 24) | ((u64)lo << 12) | (u64)hi;
                // read-check is stale-tolerant: cached value only ever >= truth
                if (g < best[cv]) atomicMin(&best[cv], g);
            }
        }
    }

    // ---------------- ticket (two-level, own-drain only) ----------------
    __syncthreads();
    asm volatile("s_waitcnt vmcnt(0)" ::: "memory");   // own atomics ack'd
    __shared__ int lastFlag;
    if (tid == 0) {
        int l = 0;
        u32 a = atomicAdd(&ws->tick1[r - 1][m][b >> 4], 1u);
        if (a == 15u) {
            u32 c2 = atomicAdd(&ws->tick2[r - 1][m], 1u);
            l = (c2 == 63u);
        }
        lastFlag = l;
    }
    __syncthreads();
    if (!lastFlag) return;

    // ---------------- hook phase (elect block only, LDS) ----------------
    __shared__ u32 nxt[N];                         // 16 KB
    __shared__ u32 red[4];
    __shared__ float fpart[4];

    if (alive) {
        u32 pay[16];
        // A: roots hook toward the other endpoint's component
        #pragma unroll
        for (int k = 0; k < 16; ++k) {
            int i = tid + (k << 8);
            u32 ci = (r == 1) ? (u32)i : cm[i];
            u32 x = (u32)i, p = 0;
            if (ci == (u32)i) {
                u64 g = __hip_atomic_load(&best[i], __ATOMIC_RELAXED,
                                          __HIP_MEMORY_SCOPE_AGENT);
                if (g != INFK) {
                    u32 lo = (u32)(g >> 12) & 0xFFFu, hi = (u32)g & 0xFFFu;
                    u32 cl = (r == 1) ? lo : cm[lo];
                    u32 ch = (r == 1) ? hi : cm[hi];
                    x = (cl == (u32)i) ? ch : cl;
                    p = (u32)(g & 0xFFFFFFu);
                }
            }
            pay[k] = p;
            nxt[i] = x;
        }
        __syncthreads();

        // B: in-place 2-cycle resolve (race-safe: only smaller mutual partner
        // writes, and only its own slot -> self). Dying root records its edge;
        // round 1 survivors get the diagonal sentinel.
        #pragma unroll
        for (int k = 0; k < 16; ++k) {
            int i = tid + (k << 8);
            u32 ci = (r == 1) ? (u32)i : cm[i];
            if (ci == (u32)i) {
                u32 o = nxt[i];
                bool dying = false;
                if (o != (u32)i) {
                    bool mutual = (nxt[o] == (u32)i);
                    if (mutual && (u32)i < o) nxt[i] = (u32)i;
                    else dying = true;
                }
                if (dying)       ws->edges[m][i] = pay[k];
                else if (r == 1) ws->edges[m][i] = ((u32)i << 12) | (u32)i;
            }
        }
        __syncthreads();

        // C: pointer jumping in place, early exit (typical depth <= 4)
        for (int s = 0; s < 12; ++s) {
            u32 changed = 0;
            #pragma unroll
            for (int k = 0; k < 16; ++k) {
                int i = tid + (k << 8);
                u32 a = nxt[i];
                u32 t = nxt[a];
                if (t != a) changed = 1u;
                nxt[i] = t;
            }
            if (!__syncthreads_or((int)changed)) break;
        }

        // D: count surviving roots
        u32 cnt = 0;
        #pragma unroll
        for (int k = 0; k < 16; ++k) {
            int i = tid + (k << 8);
            u32 ci = (r == 1) ? (u32)i : cm[i];
            if (ci == (u32)i && nxt[i] == (u32)i) cnt++;
        }
        #pragma unroll
        for (int off = 32; off >= 1; off >>= 1)
            cnt += (u32)__shfl_down((int)cnt, off, 64);
        if (lane == 0) red[wave] = cnt;
        __syncthreads();

        // E: relabel comp, reset best for old roots (plain stores: sole dirty
        // writer this dispatch; kernel-end flush publishes for next round)
        #pragma unroll
        for (int k = 0; k < 16; ++k) {
            int i = tid + (k << 8);
            u32 ci = (r == 1) ? (u32)i : cm[i];
            cm[i] = nxt[ci];
            if (ci == (u32)i) best[i] = INFK;
        }
        if (tid == 0) ws->ncomp[m] = red[0] + red[1] + red[2] + red[3];
    }

    // ---------------- fused epilogue (final round's elect block) ----------------
    if (fin) {
        __syncthreads();
        float acc = 0.f;
        #pragma unroll
        for (int k = 0; k < 16; ++k) {
            int i = tid + (k << 8);
            u32 pk = ws->edges[m][i];
            u32 lo = (pk >> 12) & 0xFFFu, hi = pk & 0xFFFu;
            size_t off = (size_t)lo * N + hi;
            float df = d1[off] - d2[off];          // diagonal sentinel -> 0
            acc += df * df;
        }
        #pragma unroll
        for (int off = 32; off >= 1; off >>= 1) acc += __shfl_down(acc, off, 64);
        if (lane == 0) fpart[wave] = acc;
        __syncthreads();
        if (tid == 0)
            atomicAdd(out, fpart[0] + fpart[1] + fpart[2] + fpart[3]);
    }
}

extern "C" void kernel_launch(void* const* d_in, const int* in_sizes, int n_in,
                              void* d_out, int out_size, void* d_ws, size_t ws_size,
                              hipStream_t stream) {
    (void)in_sizes; (void)n_in; (void)out_size; (void)ws_size;
    const float* d1 = (const float*)d_in[0];
    const float* d2 = (const float*)d_in[1];
    float* out = (float*)d_out;
    Ws* ws = (Ws*)d_ws;   // ~4.14 MB scratch (fit proven since round 6)

    hipMemsetAsync(d_out, 0, sizeof(float), stream);
    hipMemsetAsync(ws->tick1, 0, sizeof(ws->tick1) + sizeof(ws->tick2), stream);
    for (int r = 1; r <= NROUNDS; ++r)
        round_k<<<dim3(2048), dim3(256), 0, stream>>>(d1, d2, ws, out, r,
                                                      r == NROUNDS ? 1 : 0);
}

// Round 13
// 267.724 us; speedup vs baseline: 1.3317x; 1.3317x over previous
//
#include <hip/hip_runtime.h>
#include <stdint.h>

// TopoSignature via parallel Boruvka MST. Round 13: r11 champion structure
// (262 us; 3 fusion attempts all regressed — kernel boundary is the cheap
// device-wide fence on MI355X) with hook_k rebuilt:
//  - rootlist compaction: hook r iterates only ncomp_{r-1} roots in phases
//    A-D (r11 did O(N) always); only the parallel relabel stays O(N).
//  - in-place nxt[] (16 KB LDS, r12-proven race-safe 2-cycle resolve)
//    replaces compL+nxtA+nxtB (48 KB) — staging load gone.
//  - first hook uses identity comp (no comp load); scanA sheds init writes.
// scanA frozen at ~46 us (pattern ceiling, 4 experiments within noise).

#define N        4096
#define NROUNDS  12

typedef unsigned long long u64;
typedef uint32_t u32;

#define INFK (~0ull)

struct Ws {
    u64 best[2][N];      // per-component min outgoing edge key: (wbits<<24)|(lo<<12)|hi
    u32 comp[2][N];      // vertex -> component root label
    u32 edges[2][N];     // edge slot per vertex, (lo<<12)|hi; (i<<12)|i = sentinel
    u32 ncomp[2];
    u32 rootcnt[2];
    u32 pad[12];
    u32 rootlist[2][N];  // compacted surviving roots (written by each hook)
    u64 bm[2][N * 64];   // per-row per-lane-block bound keys: (wbits<<12)|col ; 4 MB
};

__device__ __forceinline__ u64 umin64(u64 a, u64 b) { return a < b ? a : b; }

__device__ __forceinline__ u64 shfl_xor_u64(u64 x, int off) {
    u32 lo = (u32)x, hi = (u32)(x >> 32);
    lo = (u32)__shfl_xor((int)lo, off, 64);
    hi = (u32)__shfl_xor((int)hi, off, 64);
    return ((u64)hi << 32) | lo;
}

// ---- round 1 full scan. One wave per row; lane-private block minima
// (block L = cols ≡ [4L,4L+4) mod 256). Pure scan: best + bm only. ----
__launch_bounds__(256, 8)
__global__ void scanA_k(const float* __restrict__ d1, const float* __restrict__ d2,
                        Ws* __restrict__ ws) {
    const int m = blockIdx.x >> 10;
    const int wave = threadIdx.x >> 6, lane = threadIdx.x & 63;
    const int v = ((blockIdx.x & 1023) << 2) + wave;
    const float4* __restrict__ row4 = (const float4*)((m ? d2 : d1) + (size_t)v * N);

    const u32 uv = (u32)v;
    u64 bmin = INFK;
    #pragma unroll
    for (int j = 0; j < 16; ++j) {
        const int c = lane + 64 * j;
        float4 w = row4[c];
        const u32 c0 = (u32)(4 * c);
        if (c0 + 0 != uv) bmin = umin64(bmin, (((u64)__float_as_uint(w.x)) << 12) | (c0 + 0));
        if (c0 + 1 != uv) bmin = umin64(bmin, (((u64)__float_as_uint(w.y)) << 12) | (c0 + 1));
        if (c0 + 2 != uv) bmin = umin64(bmin, (((u64)__float_as_uint(w.z)) << 12) | (c0 + 2));
        if (c0 + 3 != uv) bmin = umin64(bmin, (((u64)__float_as_uint(w.w)) << 12) | (c0 + 3));
    }
    ws->bm[m][(size_t)v * 64 + lane] = bmin;      // coalesced 512 B store

    u64 rowmin = bmin;
    #pragma unroll
    for (int off = 1; off <= 32; off <<= 1)
        rowmin = umin64(rowmin, shfl_xor_u64(rowmin, off));

    if (lane == 0) {
        u32 u  = (u32)rowmin & 0xFFFu;
        u64 wb = rowmin >> 12;
        u32 lo = min(uv, u), hi = max(uv, u);
        ws->best[m][v] = (wb << 24) | ((u64)lo << 12) | (u64)hi;  // unique writer
    }
}

// ---- rounds 2+: bound-table scan. One wave per row, lane = block. ----
__launch_bounds__(256, 8)
__global__ void scan2_k(const float* __restrict__ d1, const float* __restrict__ d2,
                        Ws* __restrict__ ws) {
    const int m = blockIdx.x >> 10;
    if (ws->ncomp[m] <= 1u) return;
    const int wave = threadIdx.x >> 6, lane = threadIdx.x & 63;
    const int v = ((blockIdx.x & 1023) << 2) + wave;

    const float* __restrict__ dm = m ? d2 : d1;
    const u32*   __restrict__ cm = ws->comp[m];
    u64* __restrict__ bmrow = ws->bm[m] + (size_t)v * 64;

    const u32 cv = cm[v];
    u64 key = bmrow[lane];
    bool cross = false;
    if (key != INFK) cross = (cm[(u32)key & 0xFFFu] != cv);

    u64 kb = cross ? key : INFK;                  // exact cross candidates
    #pragma unroll
    for (int off = 1; off <= 32; off <<= 1)
        kb = umin64(kb, shfl_xor_u64(kb, off));

    const bool need = (!cross) && (key < kb);     // intra bound undercuts
    u64 nm = INFK;
    if (need) {
        const float4* __restrict__ row4 = (const float4*)(dm + (size_t)v * N);
        const uint4*  __restrict__ c4   = (const uint4*)cm;
        #pragma unroll
        for (int j = 0; j < 16; ++j) {
            const int c = lane + 64 * j;
            float4 w = row4[c];
            uint4 cu = c4[c];
            u32 c0 = (u32)(4 * c);
            if (cu.x != cv) nm = umin64(nm, (((u64)__float_as_uint(w.x)) << 12) | (c0 + 0));
            if (cu.y != cv) nm = umin64(nm, (((u64)__float_as_uint(w.y)) << 12) | (c0 + 1));
            if (cu.z != cv) nm = umin64(nm, (((u64)__float_as_uint(w.z)) << 12) | (c0 + 2));
            if (cu.w != cv) nm = umin64(nm, (((u64)__float_as_uint(w.w)) << 12) | (c0 + 3));
        }
        bmrow[lane] = nm;                         // tightened bound
    }
    u64 kb2 = need ? nm : INFK;
    #pragma unroll
    for (int off = 1; off <= 32; off <<= 1)
        kb2 = umin64(kb2, shfl_xor_u64(kb2, off));

    u64 fin = umin64(kb, kb2);
    if (lane == 0 && fin != INFK) {
        u32 u  = (u32)fin & 0xFFFu;
        u64 wb = fin >> 12;
        u32 lo = min((u32)v, u), hi = max((u32)v, u);
        u64 g  = (wb << 24) | ((u64)lo << 12) | (u64)hi;
        if (g < ws->best[m][cv])                  // stale-high reads are safe
            atomicMin(&ws->best[m][cv], g);
    }
}

// ---- fallback full scan (ws too small for bound table) ----
__launch_bounds__(256, 8)
__global__ void scanF_k(const float* __restrict__ d1, const float* __restrict__ d2,
                        Ws* __restrict__ ws, int first) {
    const int m = blockIdx.x >> 10;
    if (!first && ws->ncomp[m] <= 1u) return;
    const int wave = threadIdx.x >> 6, lane = threadIdx.x & 63;
    const int v = ((blockIdx.x & 1023) << 2) + wave;
    const float* __restrict__ dm = m ? d2 : d1;
    const u32*   __restrict__ cm = ws->comp[m];
    const float4* __restrict__ row4 = (const float4*)(dm + (size_t)v * N);
    const uint4*  __restrict__ c4   = (const uint4*)cm;
    const u32 cv = first ? (u32)v : cm[v];
    u64 kmin = INFK;
    #pragma unroll
    for (int j = 0; j < 16; ++j) {
        const int c = lane + 64 * j;
        float4 w = row4[c];
        uint4 cu;
        if (!first) cu = c4[c];
        const u32 c0 = (u32)(4 * c);
        bool x0, x1, x2, x3;
        if (first) {
            x0 = (c0+0 != cv); x1 = (c0+1 != cv); x2 = (c0+2 != cv); x3 = (c0+3 != cv);
        } else {
            x0 = (cu.x != cv); x1 = (cu.y != cv); x2 = (cu.z != cv); x3 = (cu.w != cv);
        }
        if (x0) kmin = umin64(kmin, (((u64)__float_as_uint(w.x)) << 12) | (c0 + 0));
        if (x1) kmin = umin64(kmin, (((u64)__float_as_uint(w.y)) << 12) | (c0 + 1));
        if (x2) kmin = umin64(kmin, (((u64)__float_as_uint(w.z)) << 12) | (c0 + 2));
        if (x3) kmin = umin64(kmin, (((u64)__float_as_uint(w.w)) << 12) | (c0 + 3));
    }
    #pragma unroll
    for (int off = 1; off <= 32; off <<= 1)
        kmin = umin64(kmin, shfl_xor_u64(kmin, off));
    if (lane == 0 && kmin != INFK) {
        u32 u  = (u32)kmin & 0xFFFu;
        u64 wb = kmin >> 12;
        u32 lo = min((u32)v, u), hi = max((u32)v, u);
        u64 g  = (wb << 24) | ((u64)lo << 12) | (u64)hi;
        if (first) ws->best[m][v] = g;
        else if (g < ws->best[m][cv]) atomicMin(&ws->best[m][cv], g);
    }
}

// ---- hook: rootlist-driven. In-place nxt[] resolve (race-safe: each root
// writes only its own slot, and either read order yields the correct die/
// survive decision — verified r12), early-exit pointer jump, O(N) relabel,
// compacted survivor list for the next hook. One 1024-thread block/matrix.
__launch_bounds__(1024, 1)
__global__ void hook_k(const float* __restrict__ d1, const float* __restrict__ d2,
                       Ws* __restrict__ ws, float* __restrict__ out,
                       int first, int fin) {
    const int m = blockIdx.x;
    const int tid = threadIdx.x;
    const int lane = tid & 63, wave = tid >> 6;

    __shared__ u32 nxt[N];        // 16 KB
    __shared__ u32 cnt_sh;
    __shared__ float fpart[16];

    u32* __restrict__ cm   = ws->comp[m];
    u64* __restrict__ best = ws->best[m];
    u32* __restrict__ rl   = ws->rootlist[m];

    const bool alive = first || (ws->ncomp[m] > 1u);
    if (alive) {
        const u32 nr = first ? (u32)N : ws->rootcnt[m];

        // A: each root hooks toward the other endpoint's component
        for (u32 t = tid; t < nr; t += 1024) {
            u32 i = first ? t : rl[t];
            u64 g = best[i];
            u32 x = i;
            if (g != INFK) {
                u32 lo = (u32)(g >> 12) & 0xFFFu, hi = (u32)g & 0xFFFu;
                u32 cl = first ? lo : cm[lo];
                u32 ch = first ? hi : cm[hi];
                x = (cl == i) ? ch : cl;
            }
            nxt[i] = x;
        }
        __syncthreads();

        // B: in-place 2-cycle resolve; dying roots record their edge,
        // first-round survivors write the diagonal sentinel.
        for (u32 t = tid; t < nr; t += 1024) {
            u32 i = first ? t : rl[t];
            u32 o = nxt[i];
            bool die = false;
            if (o != i) {
                bool mutual = (nxt[o] == i);
                if (mutual && i < o) nxt[i] = i;        // survive
                else die = true;
            }
            if (die)             ws->edges[m][i] = (u32)(best[i] & 0xFFFFFFu);
            else if (first)      ws->edges[m][i] = (i << 12) | i;
        }
        __syncthreads();

        // C: pointer jumping over roots only, early exit (typ. depth <= 4)
        for (int s = 0; s < 12; ++s) {
            u32 changed = 0;
            for (u32 t = tid; t < nr; t += 1024) {
                u32 i = first ? t : rl[t];
                u32 a = nxt[i];
                u32 b2 = nxt[a];
                if (b2 != a) changed = 1u;
                nxt[i] = b2;
            }
            if (!__syncthreads_or((int)changed)) break;
        }

        // stage old roots (rl will be overwritten), zero the counter
        u32 myroot[4];
        int nm_ = 0;
        for (u32 t = tid; t < nr; t += 1024) myroot[nm_++] = first ? t : rl[t];
        if (tid == 0) cnt_sh = 0;
        __syncthreads();

        // D/E: compact survivors into rl, reset their best, relabel comp
        for (int q = 0; q < nm_; ++q) {
            u32 i = myroot[q];
            if (nxt[i] == i) {                    // survivor
                u32 p = atomicAdd(&cnt_sh, 1u);
                rl[p] = i;
                best[i] = INFK;
            }
        }
        for (u32 t = tid; t < (u32)N; t += 1024) {
            u32 co = first ? t : cm[t];
            cm[t] = nxt[co];
        }
        __syncthreads();
        if (tid == 0) { ws->ncomp[m] = cnt_sh; ws->rootcnt[m] = cnt_sh; }
    }

    // ---- fused epilogue on the final round (runs even when dead) ----
    if (fin) {
        __syncthreads();
        float acc = 0.f;
        #pragma unroll
        for (int k = 0; k < 4; ++k) {
            int i = tid + k * 1024;
            u32 pk = ws->edges[m][i];
            u32 lo = (pk >> 12) & 0xFFFu, hi = pk & 0xFFFu;
            size_t off = (size_t)lo * N + hi;
            float df = d1[off] - d2[off];         // diagonal sentinel -> 0
            acc += df * df;
        }
        #pragma unroll
        for (int off = 32; off >= 1; off >>= 1) acc += __shfl_down(acc, off, 64);
        if (lane == 0) fpart[wave] = acc;
        __syncthreads();
        if (tid == 0) {
            float t = 0.f;
            #pragma unroll
            for (int w = 0; w < 16; ++w) t += fpart[w];
            atomicAdd(out, t);
        }
    }
}

extern "C" void kernel_launch(void* const* d_in, const int* in_sizes, int n_in,
                              void* d_out, int out_size, void* d_ws, size_t ws_size,
                              hipStream_t stream) {
    (void)in_sizes; (void)n_in; (void)out_size;
    const float* d1 = (const float*)d_in[0];
    const float* d2 = (const float*)d_in[1];
    float* out = (float*)d_out;
    Ws* ws = (Ws*)d_ws;
    const bool big = (ws_size >= sizeof(Ws));   // ~4.36 MB needed for bound table

    hipMemsetAsync(d_out, 0, sizeof(float), stream);
    for (int r = 0; r < NROUNDS; ++r) {
        if (big) {
            if (r == 0) scanA_k<<<dim3(2048), dim3(256), 0, stream>>>(d1, d2, ws);
            else        scan2_k<<<dim3(2048), dim3(256), 0, stream>>>(d1, d2, ws);
        } else {
            scanF_k<<<dim3(2048), dim3(256), 0, stream>>>(d1, d2, ws, r == 0 ? 1 : 0);
        }
        hook_k<<<dim3(2), dim3(1024), 0, stream>>>(d1, d2, ws, out,
                                                   r == 0 ? 1 : 0,
                                                   r == NROUNDS - 1 ? 1 : 0);
    }
}